// Round 6
// baseline (33.303 us; speedup 1.0000x reference)
//
#include <hip/hip_runtime.h>

#define BLOCK 256
#define NBLK  512
#define EPSF 1e-8f

// Branch-free Liang-Barsky: clip segment p + t*d, t in [0,1], against
// |x| <= hx, |y| <= hy. Returns (tmin, tmax); empty iff tmax <= tmin.
__device__ __forceinline__ void lb_clip(float px, float py, float dx, float dy,
                                        float hx, float hy,
                                        float& tmin, float& tmax) {
    float sdx = (fabsf(dx) > 1e-30f) ? dx : copysignf(1e-30f, dx);
    float sdy = (fabsf(dy) > 1e-30f) ? dy : copysignf(1e-30f, dy);
    float rdx = __frcp_rn(sdx);
    float rdy = __frcp_rn(sdy);
    float t1x = (-hx - px) * rdx, t2x = (hx - px) * rdx;
    float t1y = (-hy - py) * rdy, t2y = (hy - py) * rdy;
    tmin = fmaxf(fmaxf(fminf(t1x, t2x), fminf(t1y, t2y)), 0.f);
    tmax = fminf(fminf(fmaxf(t1x, t2x), fmaxf(t1y, t2y)), 1.f);
}

__global__ __launch_bounds__(BLOCK) void box_loss_fused(
    const float* __restrict__ box, const float* __restrict__ tgt,
    const float* __restrict__ wgt, int n,
    const int* __restrict__ avg_factor, float* __restrict__ out)
{
    __shared__ float red[8];

    const int tid = threadIdx.x;
    const int stride = gridDim.x * BLOCK;
    float sumL1 = 0.f, sumG = 0.f;

    for (int i = blockIdx.x * BLOCK + tid; i < n; i += stride) {
        const float* bp = box + (size_t)i * 11;
        const float* tp = tgt + (size_t)i * 11;
        const float* wp = wgt + (size_t)i * 11;
        float b[11], t[11], w[11];
#pragma unroll
        for (int j = 0; j < 11; ++j) { b[j] = bp[j]; t[j] = tp[j]; w[j] = wp[j]; }

        // ---- L1 loss ----
        float lb = 0.f;
#pragma unroll
        for (int j = 0; j < 11; ++j) lb += fabsf(b[j] - t[j]) * w[j];
        sumL1 += lb;

        // ---- decode: sin(atan2(s,c)) = s*rsqrt(s^2+c^2); exp via HW ----
        float w1 = __expf(b[3]), l1v = __expf(b[4]);
        float w2 = __expf(t[3]), l2v = __expf(t[4]);
        float r1 = rsqrtf(fmaxf(b[6] * b[6] + b[7] * b[7], 1e-30f));
        float s1 = b[6] * r1, c1 = b[7] * r1;
        float r2 = rsqrtf(fmaxf(t[6] * t[6] + t[7] * t[7], 1e-30f));
        float s2 = t[6] * r2, c2 = t[7] * r2;

        float hx1 = 0.5f * w1, hy1 = 0.5f * l1v;
        float hx2 = 0.5f * w2, hy2 = 0.5f * l2v;

        // enclosing AABB (world frame), closed form
        float e1x = fabsf(hx1 * c1) + fabsf(hy1 * s1);
        float e1y = fabsf(hx1 * s1) + fabsf(hy1 * c1);
        float e2x = fabsf(hx2 * c2) + fabsf(hy2 * s2);
        float e2y = fabsf(hx2 * s2) + fabsf(hy2 * c2);
        float cx1 = b[0], cy1 = b[1], cx2 = t[0], cy2 = t[1];
        float enc = (fmaxf(cx1 + e1x, cx2 + e2x) - fminf(cx1 - e1x, cx2 - e2x))
                  * (fmaxf(cy1 + e1y, cy2 + e2y) - fminf(cy1 - e1y, cy2 - e2y));

        // rect1 pose in rect2's local frame
        float dxw = cx1 - cx2, dyw = cy1 - cy2;
        float txl =  c2 * dxw + s2 * dyw;
        float tyl = -s2 * dxw + c2 * dyw;
        float cr_ = c1 * c2 + s1 * s2;
        float sr_ = s1 * c2 - c1 * s2;

        const float UX[4] = { -1.f, 1.f, 1.f, -1.f };
        const float UY[4] = { -1.f, -1.f, 1.f, 1.f };
        float qx[4], qy[4];
#pragma unroll
        for (int k = 0; k < 4; ++k) {
            float ux = UX[k] * hx1, uy = UY[k] * hy1;
            qx[k] = txl + ux * cr_ - uy * sr_;
            qy[k] = tyl + ux * sr_ + uy * cr_;
        }

        // ---- Green's theorem intersection area ----
        float inter2 = 0.f;
        // rect1 edges clipped to |x|<=hx2, |y|<=hy2
#pragma unroll
        for (int k = 0; k < 4; ++k) {
            int kn = (k + 1) & 3;
            float px = qx[k], py = qy[k];
            float dx = qx[kn] - px, dy = qy[kn] - py;
            float t0, t1;
            lb_clip(px, py, dx, dy, hx2, hy2, t0, t1);
            float ax = fmaf(t0, dx, px), ay = fmaf(t0, dy, py);
            float bx = fmaf(t1, dx, px), by = fmaf(t1, dy, py);
            float c = ax * by - ay * bx;
            inter2 += (t1 > t0) ? c : 0.f;
        }
        // rect2 edges clipped against rect1 (t computed in rect1 local coords)
        {
            float Rx[4] = { -hx2, hx2, hx2, -hx2 };
            float Ry[4] = { -hy2, -hy2, hy2, hy2 };
            float ux[4], uy[4];
#pragma unroll
            for (int k = 0; k < 4; ++k) {
                float zx = Rx[k] - txl, zy = Ry[k] - tyl;
                ux[k] =  cr_ * zx + sr_ * zy;
                uy[k] = -sr_ * zx + cr_ * zy;
            }
#pragma unroll
            for (int k = 0; k < 4; ++k) {
                int kn = (k + 1) & 3;
                float du = ux[kn] - ux[k], dv = uy[kn] - uy[k];
                float t0, t1;
                lb_clip(ux[k], uy[k], du, dv, hx1, hy1, t0, t1);
                float dzx = Rx[kn] - Rx[k], dzy = Ry[kn] - Ry[k];
                float ax = fmaf(t0, dzx, Rx[k]), ay = fmaf(t0, dzy, Ry[k]);
                float bx = fmaf(t1, dzx, Rx[k]), by = fmaf(t1, dzy, Ry[k]);
                float c = ax * by - ay * bx;
                inter2 += (t1 > t0) ? c : 0.f;
            }
        }
        float inter = 0.5f * fabsf(inter2);

        float areaU = w1 * l1v + w2 * l2v - inter;
        float iou = inter / (areaU + EPSF);
        float giou = iou - (enc - areaU) / (enc + EPSF);
        sumG += 1.f - giou;
    }

    // ---- block reduction (wave=64) ----
#pragma unroll
    for (int off = 32; off > 0; off >>= 1) {
        sumL1 += __shfl_down(sumL1, off);
        sumG  += __shfl_down(sumG, off);
    }
    const int wave = tid >> 6, lane = tid & 63;
    if (lane == 0) { red[wave] = sumL1; red[4 + wave] = sumG; }
    __syncthreads();
    if (tid == 0) {
        float af = (float)(*avg_factor);
        if (af < 1.f) af = 1.f;
        float inv = 1.f / af;
        float a = (red[0] + red[1] + red[2] + red[3]) * inv;
        float g = (red[4] + red[5] + red[6] + red[7]) * inv;
        atomicAdd(&out[0], a);
        atomicAdd(&out[1], g);
    }
}

extern "C" void kernel_launch(void* const* d_in, const int* in_sizes, int n_in,
                              void* d_out, int out_size, void* d_ws, size_t ws_size,
                              hipStream_t stream) {
    const float* box = (const float*)d_in[0];
    const float* tgt = (const float*)d_in[1];
    const float* wgt = (const float*)d_in[2];
    const int*   af  = (const int*)d_in[3];
    float* out = (float*)d_out;

    int n = in_sizes[0] / 11;
    int nblk = NBLK;
    int maxblk = (n + BLOCK - 1) / BLOCK;
    if (nblk > maxblk) nblk = maxblk;
    if (nblk < 1) nblk = 1;

    hipMemsetAsync(out, 0, 2 * sizeof(float), stream);
    hipLaunchKernelGGL(box_loss_fused, dim3(nblk), dim3(BLOCK), 0, stream,
                       box, tgt, wgt, n, af, out);
}

// Round 7
// 22.084 us; speedup vs baseline: 1.5080x; 1.5080x over previous
//
#include <hip/hip_runtime.h>

#define BLOCK 256
#define EPSF 1e-8f

// 16-byte vector load type with only 4-byte alignment guarantee (rows are
// 44 B apart). gfx950 global loads support 4B-aligned dwordx4.
typedef float f4u __attribute__((ext_vector_type(4), aligned(4)));

// Branch-free Liang-Barsky: clip segment p + t*d, t in [0,1], against
// |x| <= hx, |y| <= hy. Returns (tmin, tmax); empty iff tmax <= tmin.
__device__ __forceinline__ void lb_clip(float px, float py, float dx, float dy,
                                        float hx, float hy,
                                        float& tmin, float& tmax) {
    float sdx = (fabsf(dx) > 1e-30f) ? dx : copysignf(1e-30f, dx);
    float sdy = (fabsf(dy) > 1e-30f) ? dy : copysignf(1e-30f, dy);
    float rdx = __frcp_rn(sdx);
    float rdy = __frcp_rn(sdy);
    float t1x = (-hx - px) * rdx, t2x = (hx - px) * rdx;
    float t1y = (-hy - py) * rdy, t2y = (hy - py) * rdy;
    tmin = fmaxf(fmaxf(fminf(t1x, t2x), fminf(t1y, t2y)), 0.f);
    tmax = fminf(fminf(fmaxf(t1x, t2x), fmaxf(t1y, t2y)), 1.f);
}

__global__ __launch_bounds__(BLOCK) void box_loss_main(
    const float* __restrict__ box, const float* __restrict__ tgt,
    const float* __restrict__ wgt, int n, float* __restrict__ partials)
{
    __shared__ float red[8];

    const int tid = threadIdx.x;
    const int i = blockIdx.x * BLOCK + tid;
    float sumL1 = 0.f, sumG = 0.f;

    if (i < n) {
        const float* bp = box + (size_t)i * 11;
        const float* tp = tgt + (size_t)i * 11;
        const float* wp = wgt + (size_t)i * 11;

        // row = [0..3], [4..7], [7..10] (elem 7 duplicated, harmless)
        f4u b0 = *(const f4u*)(bp);
        f4u b1 = *(const f4u*)(bp + 4);
        f4u b2 = *(const f4u*)(bp + 7);
        f4u t0 = *(const f4u*)(tp);
        f4u t1 = *(const f4u*)(tp + 4);
        f4u t2 = *(const f4u*)(tp + 7);
        f4u w0 = *(const f4u*)(wp);
        f4u w1 = *(const f4u*)(wp + 4);
        f4u w2 = *(const f4u*)(wp + 7);

        // ---- L1 loss over all 11 components ----
        float lb = 0.f;
        lb += fabsf(b0.x - t0.x) * w0.x;   // 0
        lb += fabsf(b0.y - t0.y) * w0.y;   // 1
        lb += fabsf(b0.z - t0.z) * w0.z;   // 2
        lb += fabsf(b0.w - t0.w) * w0.w;   // 3
        lb += fabsf(b1.x - t1.x) * w1.x;   // 4
        lb += fabsf(b1.y - t1.y) * w1.y;   // 5
        lb += fabsf(b1.z - t1.z) * w1.z;   // 6
        lb += fabsf(b1.w - t1.w) * w1.w;   // 7
        lb += fabsf(b2.y - t2.y) * w2.y;   // 8
        lb += fabsf(b2.z - t2.z) * w2.z;   // 9
        lb += fabsf(b2.w - t2.w) * w2.w;   // 10
        sumL1 = lb;

        // ---- decode: sin(atan2(s,c)) = s*rsqrt(s^2+c^2); exp via HW ----
        float cx1 = b0.x, cy1 = b0.y, cx2 = t0.x, cy2 = t0.y;
        float w1v = __expf(b0.w), l1v = __expf(b1.x);
        float w2v = __expf(t0.w), l2v = __expf(t1.x);
        float r1 = rsqrtf(fmaxf(b1.z * b1.z + b1.w * b1.w, 1e-30f));
        float s1 = b1.z * r1, c1 = b1.w * r1;
        float r2 = rsqrtf(fmaxf(t1.z * t1.z + t1.w * t1.w, 1e-30f));
        float s2 = t1.z * r2, c2 = t1.w * r2;

        float hx1 = 0.5f * w1v, hy1 = 0.5f * l1v;
        float hx2 = 0.5f * w2v, hy2 = 0.5f * l2v;

        // enclosing AABB (world frame), closed form
        float e1x = fabsf(hx1 * c1) + fabsf(hy1 * s1);
        float e1y = fabsf(hx1 * s1) + fabsf(hy1 * c1);
        float e2x = fabsf(hx2 * c2) + fabsf(hy2 * s2);
        float e2y = fabsf(hx2 * s2) + fabsf(hy2 * c2);
        float enc = (fmaxf(cx1 + e1x, cx2 + e2x) - fminf(cx1 - e1x, cx2 - e2x))
                  * (fmaxf(cy1 + e1y, cy2 + e2y) - fminf(cy1 - e1y, cy2 - e2y));

        // rect1 pose in rect2's local frame (rect2 axis-aligned there)
        float dxw = cx1 - cx2, dyw = cy1 - cy2;
        float txl =  c2 * dxw + s2 * dyw;
        float tyl = -s2 * dxw + c2 * dyw;
        float cr_ = c1 * c2 + s1 * s2;
        float sr_ = s1 * c2 - c1 * s2;

        const float UX[4] = { -1.f, 1.f, 1.f, -1.f };
        const float UY[4] = { -1.f, -1.f, 1.f, 1.f };
        float qx[4], qy[4];
#pragma unroll
        for (int k = 0; k < 4; ++k) {
            float ux = UX[k] * hx1, uy = UY[k] * hy1;
            qx[k] = txl + ux * cr_ - uy * sr_;
            qy[k] = tyl + ux * sr_ + uy * cr_;
        }

        // ---- Green's theorem intersection area ----
        float inter2 = 0.f;
        // rect1 edges clipped to |x|<=hx2, |y|<=hy2
#pragma unroll
        for (int k = 0; k < 4; ++k) {
            int kn = (k + 1) & 3;
            float px = qx[k], py = qy[k];
            float dx = qx[kn] - px, dy = qy[kn] - py;
            float ta, tb;
            lb_clip(px, py, dx, dy, hx2, hy2, ta, tb);
            float ax = fmaf(ta, dx, px), ay = fmaf(ta, dy, py);
            float bx = fmaf(tb, dx, px), by = fmaf(tb, dy, py);
            float c = ax * by - ay * bx;
            inter2 += (tb > ta) ? c : 0.f;
        }
        // rect2 edges clipped against rect1 (t computed in rect1 local coords)
        {
            float Rx[4] = { -hx2, hx2, hx2, -hx2 };
            float Ry[4] = { -hy2, -hy2, hy2, hy2 };
            float ux[4], uy[4];
#pragma unroll
            for (int k = 0; k < 4; ++k) {
                float zx = Rx[k] - txl, zy = Ry[k] - tyl;
                ux[k] =  cr_ * zx + sr_ * zy;
                uy[k] = -sr_ * zx + cr_ * zy;
            }
#pragma unroll
            for (int k = 0; k < 4; ++k) {
                int kn = (k + 1) & 3;
                float du = ux[kn] - ux[k], dv = uy[kn] - uy[k];
                float ta, tb;
                lb_clip(ux[k], uy[k], du, dv, hx1, hy1, ta, tb);
                float dzx = Rx[kn] - Rx[k], dzy = Ry[kn] - Ry[k];
                float ax = fmaf(ta, dzx, Rx[k]), ay = fmaf(ta, dzy, Ry[k]);
                float bx = fmaf(tb, dzx, Rx[k]), by = fmaf(tb, dzy, Ry[k]);
                float c = ax * by - ay * bx;
                inter2 += (tb > ta) ? c : 0.f;
            }
        }
        float inter = 0.5f * fabsf(inter2);

        float areaU = w1v * l1v + w2v * l2v - inter;
        float iou = inter / (areaU + EPSF);
        float giou = iou - (enc - areaU) / (enc + EPSF);
        sumG = 1.f - giou;
    }

    // ---- block reduction (wave=64) ----
#pragma unroll
    for (int off = 32; off > 0; off >>= 1) {
        sumL1 += __shfl_down(sumL1, off);
        sumG  += __shfl_down(sumG, off);
    }
    const int wave = tid >> 6, lane = tid & 63;
    if (lane == 0) { red[wave] = sumL1; red[4 + wave] = sumG; }
    __syncthreads();
    if (tid == 0) {
        partials[2 * (size_t)blockIdx.x]     = red[0] + red[1] + red[2] + red[3];
        partials[2 * (size_t)blockIdx.x + 1] = red[4] + red[5] + red[6] + red[7];
    }
}

// Deterministic final reduction of per-block partials + 1/af scaling.
__global__ __launch_bounds__(256) void box_loss_final(
    const float* __restrict__ partials, int nblk,
    const int* __restrict__ avg_factor, float* __restrict__ out)
{
    __shared__ float red[8];
    float a = 0.f, g = 0.f;
    for (int i = threadIdx.x; i < nblk; i += 256) {
        a += partials[2 * (size_t)i];
        g += partials[2 * (size_t)i + 1];
    }
#pragma unroll
    for (int off = 32; off > 0; off >>= 1) {
        a += __shfl_down(a, off);
        g += __shfl_down(g, off);
    }
    const int wave = threadIdx.x >> 6, lane = threadIdx.x & 63;
    if (lane == 0) { red[wave] = a; red[4 + wave] = g; }
    __syncthreads();
    if (threadIdx.x == 0) {
        float af = (float)(*avg_factor);
        if (af < 1.f) af = 1.f;
        out[0] = (red[0] + red[1] + red[2] + red[3]) / af;
        out[1] = (red[4] + red[5] + red[6] + red[7]) / af;
    }
}

extern "C" void kernel_launch(void* const* d_in, const int* in_sizes, int n_in,
                              void* d_out, int out_size, void* d_ws, size_t ws_size,
                              hipStream_t stream) {
    const float* box = (const float*)d_in[0];
    const float* tgt = (const float*)d_in[1];
    const float* wgt = (const float*)d_in[2];
    const int*   af  = (const int*)d_in[3];
    float* out = (float*)d_out;
    float* partials = (float*)d_ws;

    int n = in_sizes[0] / 11;
    int nblk = (n + BLOCK - 1) / BLOCK;
    if (nblk < 1) nblk = 1;

    hipLaunchKernelGGL(box_loss_main, dim3(nblk), dim3(BLOCK), 0, stream,
                       box, tgt, wgt, n, partials);
    hipLaunchKernelGGL(box_loss_final, dim3(1), dim3(256), 0, stream,
                       partials, nblk, af, out);
}

// Round 8
// 21.758 us; speedup vs baseline: 1.5306x; 1.0150x over previous
//
#include <hip/hip_runtime.h>

#define BLOCK 256
#define EPSF 1e-8f

// 16-byte vector load with only 4-byte alignment guarantee (rows are 44 B).
typedef float f4u __attribute__((ext_vector_type(4), aligned(4)));

// Branch-free Liang-Barsky: clip segment p + t*d, t in [0,1], against
// |x| <= hx, |y| <= hy. Empty iff tmax <= tmin.
__device__ __forceinline__ void lb_clip(float px, float py, float dx, float dy,
                                        float hx, float hy,
                                        float& tmin, float& tmax) {
    float sdx = (fabsf(dx) > 1e-30f) ? dx : copysignf(1e-30f, dx);
    float sdy = (fabsf(dy) > 1e-30f) ? dy : copysignf(1e-30f, dy);
    float rdx = __frcp_rn(sdx);
    float rdy = __frcp_rn(sdy);
    float t1x = (-hx - px) * rdx, t2x = (hx - px) * rdx;
    float t1y = (-hy - py) * rdy, t2y = (hy - py) * rdy;
    tmin = fmaxf(fmaxf(fminf(t1x, t2x), fminf(t1y, t2y)), 0.f);
    tmax = fminf(fminf(fmaxf(t1x, t2x), fmaxf(t1y, t2y)), 1.f);
}

// Full per-box computation from the 9 loaded vectors.
__device__ __forceinline__ void box_compute(
    f4u b0, f4u b1, f4u b2, f4u t0, f4u t1, f4u t2, f4u w0, f4u w1, f4u w2,
    float& l1out, float& gout)
{
    // ---- L1 loss over the 11 components ----
    float lb = 0.f;
    lb += fabsf(b0.x - t0.x) * w0.x;
    lb += fabsf(b0.y - t0.y) * w0.y;
    lb += fabsf(b0.z - t0.z) * w0.z;
    lb += fabsf(b0.w - t0.w) * w0.w;
    lb += fabsf(b1.x - t1.x) * w1.x;
    lb += fabsf(b1.y - t1.y) * w1.y;
    lb += fabsf(b1.z - t1.z) * w1.z;
    lb += fabsf(b1.w - t1.w) * w1.w;
    lb += fabsf(b2.y - t2.y) * w2.y;
    lb += fabsf(b2.z - t2.z) * w2.z;
    lb += fabsf(b2.w - t2.w) * w2.w;
    l1out = lb;

    // ---- decode: sin(atan2(s,c)) = s*rsqrt(s^2+c^2); exp via HW ----
    float cx1 = b0.x, cy1 = b0.y, cx2 = t0.x, cy2 = t0.y;
    float w1v = __expf(b0.w), l1v = __expf(b1.x);
    float w2v = __expf(t0.w), l2v = __expf(t1.x);
    float r1 = rsqrtf(fmaxf(b1.z * b1.z + b1.w * b1.w, 1e-30f));
    float s1 = b1.z * r1, c1 = b1.w * r1;
    float r2 = rsqrtf(fmaxf(t1.z * t1.z + t1.w * t1.w, 1e-30f));
    float s2 = t1.z * r2, c2 = t1.w * r2;

    float hx1 = 0.5f * w1v, hy1 = 0.5f * l1v;
    float hx2 = 0.5f * w2v, hy2 = 0.5f * l2v;

    // enclosing AABB (world frame), closed form
    float e1x = fabsf(hx1 * c1) + fabsf(hy1 * s1);
    float e1y = fabsf(hx1 * s1) + fabsf(hy1 * c1);
    float e2x = fabsf(hx2 * c2) + fabsf(hy2 * s2);
    float e2y = fabsf(hx2 * s2) + fabsf(hy2 * c2);
    float enc = (fmaxf(cx1 + e1x, cx2 + e2x) - fminf(cx1 - e1x, cx2 - e2x))
              * (fmaxf(cy1 + e1y, cy2 + e2y) - fminf(cy1 - e1y, cy2 - e2y));

    // rect1 pose in rect2's local frame (rect2 axis-aligned there)
    float dxw = cx1 - cx2, dyw = cy1 - cy2;
    float txl =  c2 * dxw + s2 * dyw;
    float tyl = -s2 * dxw + c2 * dyw;
    float cr_ = c1 * c2 + s1 * s2;
    float sr_ = s1 * c2 - c1 * s2;

    const float UX[4] = { -1.f, 1.f, 1.f, -1.f };
    const float UY[4] = { -1.f, -1.f, 1.f, 1.f };
    float qx[4], qy[4];
#pragma unroll
    for (int k = 0; k < 4; ++k) {
        float ux = UX[k] * hx1, uy = UY[k] * hy1;
        qx[k] = txl + ux * cr_ - uy * sr_;
        qy[k] = tyl + ux * sr_ + uy * cr_;
    }

    // ---- Green's theorem intersection area ----
    float inter2 = 0.f;
#pragma unroll
    for (int k = 0; k < 4; ++k) {
        int kn = (k + 1) & 3;
        float px = qx[k], py = qy[k];
        float dx = qx[kn] - px, dy = qy[kn] - py;
        float ta, tb;
        lb_clip(px, py, dx, dy, hx2, hy2, ta, tb);
        float ax = fmaf(ta, dx, px), ay = fmaf(ta, dy, py);
        float bx = fmaf(tb, dx, px), by = fmaf(tb, dy, py);
        float c = ax * by - ay * bx;
        inter2 += (tb > ta) ? c : 0.f;
    }
    {
        float Rx[4] = { -hx2, hx2, hx2, -hx2 };
        float Ry[4] = { -hy2, -hy2, hy2, hy2 };
        float ux[4], uy[4];
#pragma unroll
        for (int k = 0; k < 4; ++k) {
            float zx = Rx[k] - txl, zy = Ry[k] - tyl;
            ux[k] =  cr_ * zx + sr_ * zy;
            uy[k] = -sr_ * zx + cr_ * zy;
        }
#pragma unroll
        for (int k = 0; k < 4; ++k) {
            int kn = (k + 1) & 3;
            float du = ux[kn] - ux[k], dv = uy[kn] - uy[k];
            float ta, tb;
            lb_clip(ux[k], uy[k], du, dv, hx1, hy1, ta, tb);
            float dzx = Rx[kn] - Rx[k], dzy = Ry[kn] - Ry[k];
            float ax = fmaf(ta, dzx, Rx[k]), ay = fmaf(ta, dzy, Ry[k]);
            float bx = fmaf(tb, dzx, Rx[k]), by = fmaf(tb, dzy, Ry[k]);
            float c = ax * by - ay * bx;
            inter2 += (tb > ta) ? c : 0.f;
        }
    }
    float inter = 0.5f * fabsf(inter2);

    float areaU = w1v * l1v + w2v * l2v - inter;
    float iou = inter / (areaU + EPSF);
    float giou = iou - (enc - areaU) / (enc + EPSF);
    gout = 1.f - giou;
}

// Two boxes per thread: 18 independent row-loads issued up front, two
// independent compute chains -> latency hiding via ILP (not just TLP).
__global__ __launch_bounds__(BLOCK) void box_loss_main(
    const float* __restrict__ box, const float* __restrict__ tgt,
    const float* __restrict__ wgt, int n, int half, float* __restrict__ partials)
{
    __shared__ float red[8];

    const int tid = threadIdx.x;
    const int iA = blockIdx.x * BLOCK + tid;
    const int iB = iA + half;
    const bool hasA = iA < n;
    const bool hasB = iB < n;
    const size_t rA = (size_t)(hasA ? iA : 0) * 11;
    const size_t rB = (size_t)(hasB ? iB : 0) * 11;

    // ---- issue all 18 loads (unconditional; clamped index, masked later) ----
    const float* bpA = box + rA; const float* tpA = tgt + rA; const float* wpA = wgt + rA;
    const float* bpB = box + rB; const float* tpB = tgt + rB; const float* wpB = wgt + rB;
    f4u Ab0 = *(const f4u*)(bpA);     f4u Ab1 = *(const f4u*)(bpA + 4); f4u Ab2 = *(const f4u*)(bpA + 7);
    f4u At0 = *(const f4u*)(tpA);     f4u At1 = *(const f4u*)(tpA + 4); f4u At2 = *(const f4u*)(tpA + 7);
    f4u Aw0 = *(const f4u*)(wpA);     f4u Aw1 = *(const f4u*)(wpA + 4); f4u Aw2 = *(const f4u*)(wpA + 7);
    f4u Bb0 = *(const f4u*)(bpB);     f4u Bb1 = *(const f4u*)(bpB + 4); f4u Bb2 = *(const f4u*)(bpB + 7);
    f4u Bt0 = *(const f4u*)(tpB);     f4u Bt1 = *(const f4u*)(tpB + 4); f4u Bt2 = *(const f4u*)(tpB + 7);
    f4u Bw0 = *(const f4u*)(wpB);     f4u Bw1 = *(const f4u*)(wpB + 4); f4u Bw2 = *(const f4u*)(wpB + 7);

    float l1A, gA, l1B, gB;
    box_compute(Ab0, Ab1, Ab2, At0, At1, At2, Aw0, Aw1, Aw2, l1A, gA);
    box_compute(Bb0, Bb1, Bb2, Bt0, Bt1, Bt2, Bw0, Bw1, Bw2, l1B, gB);

    float sumL1 = (hasA ? l1A : 0.f) + (hasB ? l1B : 0.f);
    float sumG  = (hasA ? gA  : 0.f) + (hasB ? gB  : 0.f);

    // ---- block reduction (wave=64) ----
#pragma unroll
    for (int off = 32; off > 0; off >>= 1) {
        sumL1 += __shfl_down(sumL1, off);
        sumG  += __shfl_down(sumG, off);
    }
    const int wave = tid >> 6, lane = tid & 63;
    if (lane == 0) { red[wave] = sumL1; red[4 + wave] = sumG; }
    __syncthreads();
    if (tid == 0) {
        partials[2 * (size_t)blockIdx.x]     = red[0] + red[1] + red[2] + red[3];
        partials[2 * (size_t)blockIdx.x + 1] = red[4] + red[5] + red[6] + red[7];
    }
}

// Deterministic final reduction of per-block partials + 1/af scaling.
__global__ __launch_bounds__(256) void box_loss_final(
    const float* __restrict__ partials, int nblk,
    const int* __restrict__ avg_factor, float* __restrict__ out)
{
    __shared__ float red[8];
    float a = 0.f, g = 0.f;
    for (int i = threadIdx.x; i < nblk; i += 256) {
        a += partials[2 * (size_t)i];
        g += partials[2 * (size_t)i + 1];
    }
#pragma unroll
    for (int off = 32; off > 0; off >>= 1) {
        a += __shfl_down(a, off);
        g += __shfl_down(g, off);
    }
    const int wave = threadIdx.x >> 6, lane = threadIdx.x & 63;
    if (lane == 0) { red[wave] = a; red[4 + wave] = g; }
    __syncthreads();
    if (threadIdx.x == 0) {
        float af = (float)(*avg_factor);
        if (af < 1.f) af = 1.f;
        out[0] = (red[0] + red[1] + red[2] + red[3]) / af;
        out[1] = (red[4] + red[5] + red[6] + red[7]) / af;
    }
}

extern "C" void kernel_launch(void* const* d_in, const int* in_sizes, int n_in,
                              void* d_out, int out_size, void* d_ws, size_t ws_size,
                              hipStream_t stream) {
    const float* box = (const float*)d_in[0];
    const float* tgt = (const float*)d_in[1];
    const float* wgt = (const float*)d_in[2];
    const int*   af  = (const int*)d_in[3];
    float* out = (float*)d_out;
    float* partials = (float*)d_ws;

    int n = in_sizes[0] / 11;
    int half = (n + 1) >> 1;
    int nblk = (half + BLOCK - 1) / BLOCK;
    if (nblk < 1) nblk = 1;

    hipLaunchKernelGGL(box_loss_main, dim3(nblk), dim3(BLOCK), 0, stream,
                       box, tgt, wgt, n, half, partials);
    hipLaunchKernelGGL(box_loss_final, dim3(1), dim3(256), 0, stream,
                       partials, nblk, af, out);
}

// Round 9
// 19.630 us; speedup vs baseline: 1.6965x; 1.1084x over previous
//
#include <hip/hip_runtime.h>

#define BLOCK 256
#define ITERS 4
#define EPSF 1e-8f

// 16-byte vector load with only 4-byte alignment guarantee (rows are 44 B).
typedef float f4u __attribute__((ext_vector_type(4), aligned(4)));

struct Row9 { f4u b0, b1, b2, t0, t1, t2, w0, w1, w2; };

__device__ __forceinline__ Row9 load_row(const float* __restrict__ box,
                                         const float* __restrict__ tgt,
                                         const float* __restrict__ wgt,
                                         size_t r) {
    Row9 R;
    R.b0 = *(const f4u*)(box + r); R.b1 = *(const f4u*)(box + r + 4); R.b2 = *(const f4u*)(box + r + 7);
    R.t0 = *(const f4u*)(tgt + r); R.t1 = *(const f4u*)(tgt + r + 4); R.t2 = *(const f4u*)(tgt + r + 7);
    R.w0 = *(const f4u*)(wgt + r); R.w1 = *(const f4u*)(wgt + r + 4); R.w2 = *(const f4u*)(wgt + r + 7);
    return R;
}

__device__ __forceinline__ float safe_rcp(float d) {
    float sd = (fabsf(d) > 1e-30f) ? d : copysignf(1e-30f, d);
    return __frcp_rn(sd);
}

// Clipped-length of segment p + t*d, t in [0,1], against |x|<=hx, |y|<=hy,
// with precomputed reciprocals of d. Returns max(tmax-tmin, 0).
__device__ __forceinline__ float clip_len(float px, float py,
                                          float rdx, float rdy,
                                          float hx, float hy) {
    float t1x = (-hx - px) * rdx, t2x = (hx - px) * rdx;
    float t1y = (-hy - py) * rdy, t2y = (hy - py) * rdy;
    float tmin = fmaxf(fmaxf(fminf(t1x, t2x), fminf(t1y, t2y)), 0.f);
    float tmax = fminf(fminf(fmaxf(t1x, t2x), fmaxf(t1y, t2y)), 1.f);
    return fmaxf(tmax - tmin, 0.f);
}

__device__ __forceinline__ void box_compute(const Row9& R, float& l1out, float& gout)
{
    f4u b0 = R.b0, b1 = R.b1, b2 = R.b2;
    f4u t0 = R.t0, t1 = R.t1, t2 = R.t2;
    f4u w0 = R.w0, w1 = R.w1, w2 = R.w2;

    // ---- L1 loss over the 11 components ----
    float lb = 0.f;
    lb += fabsf(b0.x - t0.x) * w0.x;
    lb += fabsf(b0.y - t0.y) * w0.y;
    lb += fabsf(b0.z - t0.z) * w0.z;
    lb += fabsf(b0.w - t0.w) * w0.w;
    lb += fabsf(b1.x - t1.x) * w1.x;
    lb += fabsf(b1.y - t1.y) * w1.y;
    lb += fabsf(b1.z - t1.z) * w1.z;
    lb += fabsf(b1.w - t1.w) * w1.w;
    lb += fabsf(b2.y - t2.y) * w2.y;
    lb += fabsf(b2.z - t2.z) * w2.z;
    lb += fabsf(b2.w - t2.w) * w2.w;
    l1out = lb;

    // ---- decode: sin(atan2(s,c)) = s*rsqrt(s^2+c^2); exp via HW ----
    float cx1 = b0.x, cy1 = b0.y, cx2 = t0.x, cy2 = t0.y;
    float w1v = __expf(b0.w), l1v = __expf(b1.x);
    float w2v = __expf(t0.w), l2v = __expf(t1.x);
    float r1 = rsqrtf(fmaxf(b1.z * b1.z + b1.w * b1.w, 1e-30f));
    float s1 = b1.z * r1, c1 = b1.w * r1;
    float r2 = rsqrtf(fmaxf(t1.z * t1.z + t1.w * t1.w, 1e-30f));
    float s2 = t1.z * r2, c2 = t1.w * r2;

    float hx1 = 0.5f * w1v, hy1 = 0.5f * l1v;
    float hx2 = 0.5f * w2v, hy2 = 0.5f * l2v;

    // enclosing AABB (world frame), closed form
    float e1x = fabsf(hx1 * c1) + fabsf(hy1 * s1);
    float e1y = fabsf(hx1 * s1) + fabsf(hy1 * c1);
    float e2x = fabsf(hx2 * c2) + fabsf(hy2 * s2);
    float e2y = fabsf(hx2 * s2) + fabsf(hy2 * c2);
    float enc = (fmaxf(cx1 + e1x, cx2 + e2x) - fminf(cx1 - e1x, cx2 - e2x))
              * (fmaxf(cy1 + e1y, cy2 + e2y) - fminf(cy1 - e1y, cy2 - e2y));

    // rect1 pose in rect2's local frame (rect2 axis-aligned there)
    float dxw = cx1 - cx2, dyw = cy1 - cy2;
    float txl =  c2 * dxw + s2 * dyw;
    float tyl = -s2 * dxw + c2 * dyw;
    float cr_ = c1 * c2 + s1 * s2;     // cos(yaw1 - yaw2)
    float sr_ = s1 * c2 - c1 * s2;     // sin(yaw1 - yaw2)

    // rect1 corners in frame2 via shared products
    float ax_ = hx1 * cr_, ay_ = hx1 * sr_;
    float bx_ = hy1 * sr_, by_ = hy1 * cr_;
    float q0x = txl - ax_ + bx_, q0y = tyl - ay_ - by_;
    float q1x = txl + ax_ + bx_, q1y = tyl + ay_ - by_;
    float q2x = txl + ax_ - bx_, q2y = tyl + ay_ + by_;
    float q3x = txl - ax_ - bx_, q3y = tyl - ay_ + by_;

    // ---- Green's theorem: inter2 = sum over boundary segments of
    // (tb-ta)*cross(p,d), all crosses evaluated in frame2 ----
    float inter2 = 0.f;

    // Part 1: rect1 edges vs rect2's box. d01 = q1-q0, d12 = q2-q1;
    // edges 2,3 are antiparallel to 0,1 -> negate reciprocals.
    {
        float d01x = 2.f * ax_, d01y = 2.f * ay_;
        float d12x = -2.f * bx_, d12y = 2.f * by_;
        float r01x = safe_rcp(d01x), r01y = safe_rcp(d01y);
        float r12x = safe_rcp(d12x), r12y = safe_rcp(d12y);

        float L0 = clip_len(q0x, q0y,  r01x,  r01y, hx2, hy2);
        inter2 += L0 * (q0x * d01y - q0y * d01x);
        float L1 = clip_len(q1x, q1y,  r12x,  r12y, hx2, hy2);
        inter2 += L1 * (q1x * d12y - q1y * d12x);
        float L2 = clip_len(q2x, q2y, -r01x, -r01y, hx2, hy2);
        inter2 += L2 * (q2y * d01x - q2x * d01y);
        float L3 = clip_len(q3x, q3y, -r12x, -r12y, hx2, hy2);
        inter2 += L3 * (q3y * d12x - q3x * d12y);
    }

    // Part 2: rect2 edges vs rect1's box (t computed in frame1);
    // cross(p,d) == 2*hx2*hy2 for every axis-aligned rect2 edge (frame2).
    {
        float zx = -hx2 - txl, zy = -hy2 - tyl;
        float u0x =  cr_ * zx + sr_ * zy;
        float u0y = -sr_ * zx + cr_ * zy;
        float E0x =  2.f * hx2 * cr_, E0y = -2.f * hx2 * sr_;
        float E1x =  2.f * hy2 * sr_, E1y =  2.f * hy2 * cr_;
        float u1x = u0x + E0x, u1y = u0y + E0y;
        float u2x = u1x + E1x, u2y = u1y + E1y;
        float u3x = u0x + E1x, u3y = u0y + E1y;
        float re0x = safe_rcp(E0x), re0y = safe_rcp(E0y);
        float re1x = safe_rcp(E1x), re1y = safe_rcp(E1y);

        float tsum = 0.f;
        tsum += clip_len(u0x, u0y,  re0x,  re0y, hx1, hy1);
        tsum += clip_len(u1x, u1y,  re1x,  re1y, hx1, hy1);
        tsum += clip_len(u2x, u2y, -re0x, -re0y, hx1, hy1);
        tsum += clip_len(u3x, u3y, -re1x, -re1y, hx1, hy1);
        inter2 += 2.f * hx2 * hy2 * tsum;
    }

    float inter = 0.5f * fabsf(inter2);
    float areaU = w1v * l1v + w2v * l2v - inter;
    float iou = inter / (areaU + EPSF);
    float giou = iou - (enc - areaU) / (enc + EPSF);
    gout = 1.f - giou;
}

// Persistent pipelined kernel: ITERS boxes/thread; iteration k prefetches
// row k+1 while computing row k (rolling load/compute overlap).
__global__ __launch_bounds__(BLOCK) void box_loss_main(
    const float* __restrict__ box, const float* __restrict__ tgt,
    const float* __restrict__ wgt, int n, int T, float* __restrict__ partials)
{
    __shared__ float red[8];

    const int tid = threadIdx.x;
    int i = blockIdx.x * BLOCK + tid;
    float sumL1 = 0.f, sumG = 0.f;

    bool v = i < n;
    Row9 cur = load_row(box, tgt, wgt, (size_t)(v ? i : 0) * 11);

#pragma unroll
    for (int k = 0; k < ITERS; ++k) {
        int inext = i + T;
        bool vnext = false;
        Row9 nxt;
        if (k + 1 < ITERS) {
            vnext = inext < n;
            nxt = load_row(box, tgt, wgt, (size_t)(vnext ? inext : 0) * 11);
        }
        float l1, g;
        box_compute(cur, l1, g);
        sumL1 += v ? l1 : 0.f;
        sumG  += v ? g  : 0.f;
        if (k + 1 < ITERS) { cur = nxt; v = vnext; i = inext; }
    }

    // ---- block reduction (wave=64) ----
#pragma unroll
    for (int off = 32; off > 0; off >>= 1) {
        sumL1 += __shfl_down(sumL1, off);
        sumG  += __shfl_down(sumG, off);
    }
    const int wave = tid >> 6, lane = tid & 63;
    if (lane == 0) { red[wave] = sumL1; red[4 + wave] = sumG; }
    __syncthreads();
    if (tid == 0) {
        partials[2 * (size_t)blockIdx.x]     = red[0] + red[1] + red[2] + red[3];
        partials[2 * (size_t)blockIdx.x + 1] = red[4] + red[5] + red[6] + red[7];
    }
}

// Deterministic final reduction of per-block partials + 1/af scaling.
__global__ __launch_bounds__(256) void box_loss_final(
    const float* __restrict__ partials, int nblk,
    const int* __restrict__ avg_factor, float* __restrict__ out)
{
    __shared__ float red[8];
    float a = 0.f, g = 0.f;
    for (int i = threadIdx.x; i < nblk; i += 256) {
        a += partials[2 * (size_t)i];
        g += partials[2 * (size_t)i + 1];
    }
#pragma unroll
    for (int off = 32; off > 0; off >>= 1) {
        a += __shfl_down(a, off);
        g += __shfl_down(g, off);
    }
    const int wave = threadIdx.x >> 6, lane = threadIdx.x & 63;
    if (lane == 0) { red[wave] = a; red[4 + wave] = g; }
    __syncthreads();
    if (threadIdx.x == 0) {
        float af = (float)(*avg_factor);
        if (af < 1.f) af = 1.f;
        out[0] = (red[0] + red[1] + red[2] + red[3]) / af;
        out[1] = (red[4] + red[5] + red[6] + red[7]) / af;
    }
}

extern "C" void kernel_launch(void* const* d_in, const int* in_sizes, int n_in,
                              void* d_out, int out_size, void* d_ws, size_t ws_size,
                              hipStream_t stream) {
    const float* box = (const float*)d_in[0];
    const float* tgt = (const float*)d_in[1];
    const float* wgt = (const float*)d_in[2];
    const int*   af  = (const int*)d_in[3];
    float* out = (float*)d_out;
    float* partials = (float*)d_ws;

    int n = in_sizes[0] / 11;
    int nblk = (n + BLOCK * ITERS - 1) / (BLOCK * ITERS);
    if (nblk < 1) nblk = 1;
    int T = nblk * BLOCK;   // total threads; thread handles i, i+T, i+2T, i+3T

    hipLaunchKernelGGL(box_loss_main, dim3(nblk), dim3(BLOCK), 0, stream,
                       box, tgt, wgt, n, T, partials);
    hipLaunchKernelGGL(box_loss_final, dim3(1), dim3(256), 0, stream,
                       partials, nblk, af, out);
}

// Round 10
// 19.403 us; speedup vs baseline: 1.7164x; 1.0117x over previous
//
#include <hip/hip_runtime.h>

#define BLOCK 256
#define ITERS 2
#define EPSF 1e-8f

// 16-byte vector load with only 4-byte alignment guarantee (rows are 44 B).
typedef float f4u __attribute__((ext_vector_type(4), aligned(4)));

struct Row9 { f4u b0, b1, b2, t0, t1, t2, w0, w1, w2; };

__device__ __forceinline__ Row9 load_row(const float* __restrict__ box,
                                         const float* __restrict__ tgt,
                                         const float* __restrict__ wgt,
                                         size_t r) {
    Row9 R;
    R.b0 = *(const f4u*)(box + r); R.b1 = *(const f4u*)(box + r + 4); R.b2 = *(const f4u*)(box + r + 7);
    R.t0 = *(const f4u*)(tgt + r); R.t1 = *(const f4u*)(tgt + r + 4); R.t2 = *(const f4u*)(tgt + r + 7);
    R.w0 = *(const f4u*)(wgt + r); R.w1 = *(const f4u*)(wgt + r + 4); R.w2 = *(const f4u*)(wgt + r + 7);
    return R;
}

__device__ __forceinline__ float safe_rcp(float d) {
    float sd = (fabsf(d) > 1e-30f) ? d : copysignf(1e-30f, d);
    return __frcp_rn(sd);
}

// Clipped-length of segment p + t*d, t in [0,1], against |x|<=hx, |y|<=hy,
// with precomputed reciprocals of d. Returns max(tmax-tmin, 0).
__device__ __forceinline__ float clip_len(float px, float py,
                                          float rdx, float rdy,
                                          float hx, float hy) {
    float t1x = (-hx - px) * rdx, t2x = (hx - px) * rdx;
    float t1y = (-hy - py) * rdy, t2y = (hy - py) * rdy;
    float tmin = fmaxf(fmaxf(fminf(t1x, t2x), fminf(t1y, t2y)), 0.f);
    float tmax = fminf(fminf(fmaxf(t1x, t2x), fmaxf(t1y, t2y)), 1.f);
    return fmaxf(tmax - tmin, 0.f);
}

__device__ __forceinline__ void box_compute(const Row9& R, float& l1out, float& gout)
{
    f4u b0 = R.b0, b1 = R.b1, b2 = R.b2;
    f4u t0 = R.t0, t1 = R.t1, t2 = R.t2;
    f4u w0 = R.w0, w1 = R.w1, w2 = R.w2;

    // ---- L1 loss over the 11 components ----
    float lb = 0.f;
    lb += fabsf(b0.x - t0.x) * w0.x;
    lb += fabsf(b0.y - t0.y) * w0.y;
    lb += fabsf(b0.z - t0.z) * w0.z;
    lb += fabsf(b0.w - t0.w) * w0.w;
    lb += fabsf(b1.x - t1.x) * w1.x;
    lb += fabsf(b1.y - t1.y) * w1.y;
    lb += fabsf(b1.z - t1.z) * w1.z;
    lb += fabsf(b1.w - t1.w) * w1.w;
    lb += fabsf(b2.y - t2.y) * w2.y;
    lb += fabsf(b2.z - t2.z) * w2.z;
    lb += fabsf(b2.w - t2.w) * w2.w;
    l1out = lb;

    // ---- decode: sin(atan2(s,c)) = s*rsqrt(s^2+c^2); exp via HW ----
    float cx1 = b0.x, cy1 = b0.y, cx2 = t0.x, cy2 = t0.y;
    float w1v = __expf(b0.w), l1v = __expf(b1.x);
    float w2v = __expf(t0.w), l2v = __expf(t1.x);
    float r1 = rsqrtf(fmaxf(b1.z * b1.z + b1.w * b1.w, 1e-30f));
    float s1 = b1.z * r1, c1 = b1.w * r1;
    float r2 = rsqrtf(fmaxf(t1.z * t1.z + t1.w * t1.w, 1e-30f));
    float s2 = t1.z * r2, c2 = t1.w * r2;

    float hx1 = 0.5f * w1v, hy1 = 0.5f * l1v;
    float hx2 = 0.5f * w2v, hy2 = 0.5f * l2v;

    // enclosing AABB (world frame), closed form
    float e1x = fabsf(hx1 * c1) + fabsf(hy1 * s1);
    float e1y = fabsf(hx1 * s1) + fabsf(hy1 * c1);
    float e2x = fabsf(hx2 * c2) + fabsf(hy2 * s2);
    float e2y = fabsf(hx2 * s2) + fabsf(hy2 * c2);
    float enc = (fmaxf(cx1 + e1x, cx2 + e2x) - fminf(cx1 - e1x, cx2 - e2x))
              * (fmaxf(cy1 + e1y, cy2 + e2y) - fminf(cy1 - e1y, cy2 - e2y));

    // rect1 pose in rect2's local frame (rect2 axis-aligned there)
    float dxw = cx1 - cx2, dyw = cy1 - cy2;
    float txl =  c2 * dxw + s2 * dyw;
    float tyl = -s2 * dxw + c2 * dyw;
    float cr_ = c1 * c2 + s1 * s2;     // cos(yaw1 - yaw2)
    float sr_ = s1 * c2 - c1 * s2;     // sin(yaw1 - yaw2)

    // rect1 corners in frame2 via shared products
    float ax_ = hx1 * cr_, ay_ = hx1 * sr_;
    float bx_ = hy1 * sr_, by_ = hy1 * cr_;
    float q0x = txl - ax_ + bx_, q0y = tyl - ay_ - by_;
    float q1x = txl + ax_ + bx_, q1y = tyl + ay_ - by_;
    float q2x = txl + ax_ - bx_, q2y = tyl + ay_ + by_;
    float q3x = txl - ax_ - bx_, q3y = tyl - ay_ + by_;

    // ---- Green's theorem: inter2 = sum over boundary segments of
    // (tb-ta)*cross(p,d), all crosses evaluated in frame2 ----
    float inter2 = 0.f;

    // Part 1: rect1 edges vs rect2's box. d01 = q1-q0, d12 = q2-q1;
    // edges 2,3 are antiparallel to 0,1 -> negate reciprocals.
    {
        float d01x = 2.f * ax_, d01y = 2.f * ay_;
        float d12x = -2.f * bx_, d12y = 2.f * by_;
        float r01x = safe_rcp(d01x), r01y = safe_rcp(d01y);
        float r12x = safe_rcp(d12x), r12y = safe_rcp(d12y);

        float L0 = clip_len(q0x, q0y,  r01x,  r01y, hx2, hy2);
        inter2 += L0 * (q0x * d01y - q0y * d01x);
        float L1 = clip_len(q1x, q1y,  r12x,  r12y, hx2, hy2);
        inter2 += L1 * (q1x * d12y - q1y * d12x);
        float L2 = clip_len(q2x, q2y, -r01x, -r01y, hx2, hy2);
        inter2 += L2 * (q2y * d01x - q2x * d01y);
        float L3 = clip_len(q3x, q3y, -r12x, -r12y, hx2, hy2);
        inter2 += L3 * (q3y * d12x - q3x * d12y);
    }

    // Part 2: rect2 edges vs rect1's box (t computed in frame1);
    // cross(p,d) == 2*hx2*hy2 for every axis-aligned rect2 edge (frame2).
    {
        float zx = -hx2 - txl, zy = -hy2 - tyl;
        float u0x =  cr_ * zx + sr_ * zy;
        float u0y = -sr_ * zx + cr_ * zy;
        float E0x =  2.f * hx2 * cr_, E0y = -2.f * hx2 * sr_;
        float E1x =  2.f * hy2 * sr_, E1y =  2.f * hy2 * cr_;
        float u1x = u0x + E0x, u1y = u0y + E0y;
        float u2x = u1x + E1x, u2y = u1y + E1y;
        float u3x = u0x + E1x, u3y = u0y + E1y;
        float re0x = safe_rcp(E0x), re0y = safe_rcp(E0y);
        float re1x = safe_rcp(E1x), re1y = safe_rcp(E1y);

        float tsum = 0.f;
        tsum += clip_len(u0x, u0y,  re0x,  re0y, hx1, hy1);
        tsum += clip_len(u1x, u1y,  re1x,  re1y, hx1, hy1);
        tsum += clip_len(u2x, u2y, -re0x, -re0y, hx1, hy1);
        tsum += clip_len(u3x, u3y, -re1x, -re1y, hx1, hy1);
        inter2 += 2.f * hx2 * hy2 * tsum;
    }

    float inter = 0.5f * fabsf(inter2);
    float areaU = w1v * l1v + w2v * l2v - inter;
    float iou = inter / (areaU + EPSF);
    float giou = iou - (enc - areaU) / (enc + EPSF);
    gout = 1.f - giou;
}

// Rolling pipeline, ITERS boxes/thread, 4 blocks/CU co-resident
// (__launch_bounds__(BLOCK,4) caps VGPR at 128 -> 4 waves/SIMD).
__global__ __launch_bounds__(BLOCK, 4) void box_loss_main(
    const float* __restrict__ box, const float* __restrict__ tgt,
    const float* __restrict__ wgt, int n, int T, float* __restrict__ partials)
{
    __shared__ float red[8];

    const int tid = threadIdx.x;
    int i = blockIdx.x * BLOCK + tid;
    float sumL1 = 0.f, sumG = 0.f;

    bool v = i < n;
    Row9 cur = load_row(box, tgt, wgt, (size_t)(v ? i : 0) * 11);

#pragma unroll
    for (int k = 0; k < ITERS; ++k) {
        int inext = i + T;
        bool vnext = false;
        Row9 nxt;
        if (k + 1 < ITERS) {
            vnext = inext < n;
            nxt = load_row(box, tgt, wgt, (size_t)(vnext ? inext : 0) * 11);
        }
        float l1, g;
        box_compute(cur, l1, g);
        sumL1 += v ? l1 : 0.f;
        sumG  += v ? g  : 0.f;
        if (k + 1 < ITERS) { cur = nxt; v = vnext; i = inext; }
    }

    // ---- block reduction (wave=64) ----
#pragma unroll
    for (int off = 32; off > 0; off >>= 1) {
        sumL1 += __shfl_down(sumL1, off);
        sumG  += __shfl_down(sumG, off);
    }
    const int wave = tid >> 6, lane = tid & 63;
    if (lane == 0) { red[wave] = sumL1; red[4 + wave] = sumG; }
    __syncthreads();
    if (tid == 0) {
        partials[2 * (size_t)blockIdx.x]     = red[0] + red[1] + red[2] + red[3];
        partials[2 * (size_t)blockIdx.x + 1] = red[4] + red[5] + red[6] + red[7];
    }
}

// Deterministic final reduction of per-block partials + 1/af scaling.
__global__ __launch_bounds__(256) void box_loss_final(
    const float* __restrict__ partials, int nblk,
    const int* __restrict__ avg_factor, float* __restrict__ out)
{
    __shared__ float red[8];
    float a = 0.f, g = 0.f;
    for (int i = threadIdx.x; i < nblk; i += 256) {
        a += partials[2 * (size_t)i];
        g += partials[2 * (size_t)i + 1];
    }
#pragma unroll
    for (int off = 32; off > 0; off >>= 1) {
        a += __shfl_down(a, off);
        g += __shfl_down(g, off);
    }
    const int wave = threadIdx.x >> 6, lane = threadIdx.x & 63;
    if (lane == 0) { red[wave] = a; red[4 + wave] = g; }
    __syncthreads();
    if (threadIdx.x == 0) {
        float af = (float)(*avg_factor);
        if (af < 1.f) af = 1.f;
        out[0] = (red[0] + red[1] + red[2] + red[3]) / af;
        out[1] = (red[4] + red[5] + red[6] + red[7]) / af;
    }
}

extern "C" void kernel_launch(void* const* d_in, const int* in_sizes, int n_in,
                              void* d_out, int out_size, void* d_ws, size_t ws_size,
                              hipStream_t stream) {
    const float* box = (const float*)d_in[0];
    const float* tgt = (const float*)d_in[1];
    const float* wgt = (const float*)d_in[2];
    const int*   af  = (const int*)d_in[3];
    float* out = (float*)d_out;
    float* partials = (float*)d_ws;

    int n = in_sizes[0] / 11;
    int nblk = (n + BLOCK * ITERS - 1) / (BLOCK * ITERS);   // 1024 for N=524288
    if (nblk < 1) nblk = 1;
    int T = nblk * BLOCK;   // thread handles i and i+T

    hipLaunchKernelGGL(box_loss_main, dim3(nblk), dim3(BLOCK), 0, stream,
                       box, tgt, wgt, n, T, partials);
    hipLaunchKernelGGL(box_loss_final, dim3(1), dim3(256), 0, stream,
                       partials, nblk, af, out);
}